// Round 2
// baseline (398.047 us; speedup 1.0000x reference)
//
#include <hip/hip_runtime.h>

// Pure embedding gather:
//   indices: [819200] int32, values in [0, 1_000_000)
//   table:   [1_000_000, 64] float32  (244 MiB)
//   out:     [819200, 64] float32     (200 MiB)
//
// Layout: 16 lanes per embedding row (64 floats = 16 float4 = 256 B), each
// lane moves one float4. Grid-stride persistent blocks; each thread batches
// G=8 independent gathers per loop iteration so the wave keeps 8 KB of
// gathered reads in flight instead of dying after a single dependent
// index->table->store chain.
//
// Stores are nontemporal: the 200 MB output stream must not write-allocate
// and evict the 244 MiB table from the 256 MiB Infinity Cache, so the ~1.47x
// average index multiplicity gets served from LLC.
//
// NOTE: __builtin_nontemporal_store requires a clang vector type, not HIP's
// float4 class — use ext_vector_type(4) and reinterpret_cast.

typedef float vfloat4 __attribute__((ext_vector_type(4)));

#define GATHER_BATCH 8

__global__ __launch_bounds__(256) void ShardedCXLEmbedding_gather(
    const int* __restrict__ indices,
    const vfloat4* __restrict__ table,   // [num_emb * 16] float4
    vfloat4* __restrict__ out,           // [n_rows * 16] float4
    int n_f4)                            // n_rows * 16
{
    const int stride = gridDim.x * 256;
    int g = blockIdx.x * 256 + threadIdx.x;

    // Main batched loop: 8 independent gathers in flight per thread.
    while (g + (GATHER_BATCH - 1) * stride < n_f4) {
        int gs[GATHER_BATCH];
        int es[GATHER_BATCH];
        vfloat4 vs[GATHER_BATCH];

        #pragma unroll
        for (int k = 0; k < GATHER_BATCH; ++k) {
            gs[k] = g + k * stride;
            es[k] = indices[gs[k] >> 4];       // 16-lane broadcast reads
        }
        #pragma unroll
        for (int k = 0; k < GATHER_BATCH; ++k) {
            vs[k] = table[(long long)es[k] * 16 + (gs[k] & 15)];
        }
        #pragma unroll
        for (int k = 0; k < GATHER_BATCH; ++k) {
            __builtin_nontemporal_store(vs[k], &out[gs[k]]);
        }
        g += GATHER_BATCH * stride;
    }

    // Tail: remaining strided elements, one at a time.
    while (g < n_f4) {
        int e = indices[g >> 4];
        vfloat4 v = table[(long long)e * 16 + (g & 15)];
        __builtin_nontemporal_store(v, &out[g]);
        g += stride;
    }
}

extern "C" void kernel_launch(void* const* d_in, const int* in_sizes, int n_in,
                              void* d_out, int out_size, void* d_ws, size_t ws_size,
                              hipStream_t stream) {
    const int*     indices = (const int*)d_in[0];
    const vfloat4* table   = (const vfloat4*)d_in[1];
    vfloat4*       out     = (vfloat4*)d_out;

    const int n_rows = in_sizes[0];              // 819200
    const long long n_f4 = (long long)n_rows * 16;

    const int block  = 256;
    // 8 blocks/CU x 256 CUs: fully resident persistent grid.
    int grid = 2048;
    const long long work_blocks = (n_f4 + block - 1) / block;
    if (work_blocks < grid) grid = (int)work_blocks;

    ShardedCXLEmbedding_gather<<<grid, block, 0, stream>>>(
        indices, table, out, (int)n_f4);
}